// Round 18
// baseline (176.639 us; speedup 1.0000x reference)
//
#include <hip/hip_runtime.h>
#include <stdint.h>

#define N_ 4096
#define B_ 1024
#define NSTEPS_ 10
#define DEG_SLOTS 40    // padded neighbor-list slots (deg ~ Poisson(12); P(>40) ~ 1e-11)
#define UNR 16          // static unrolled gather depth (sentinel-padded)
#define PAD_E ((uint32_t)(N_ * B_))   // sentinel -> byte offset of zero pad row
#define NBLK 512
#define NCTR 16
#define FLAGI 512

// ws layout (bytes):
//   bar  : 0      .. 4224     u32[1056]: 16 ctrs at stride 32 + flag at [512]
//   deg  : 8192   .. 24576    u32[N]
//   nbr  : 24576  .. 679936   u32[N][DEG_SLOTS] entry = m*B (byte off); sentinel N*B
//   sExp : 679936 .. ~9.07MB  u8[2][(N+1)*B] spike BYTES [n][b]; row N_ always zero
#define OFF_BAR  0
#define OFF_DEG  8192
#define OFF_NBR  24576
#define OFF_SEXP 679936
#define SEXP_BUF ((N_ + 1) * B_)

// build_k: neighbor lists from C (4096 blocks, full HBM BW). Block 0 zeros the
// barrier state; blocks 1,2 zero the sExp pad rows (consumed next dispatch).
__global__ __launch_bounds__(256) void build_k(const float* __restrict__ C,
                                               uint32_t* __restrict__ deg,
                                               uint32_t* __restrict__ nbr,
                                               uint32_t* __restrict__ bar,
                                               uint32_t* __restrict__ pad0,
                                               uint32_t* __restrict__ pad1) {
    __shared__ uint32_t cnt;
    int tid = threadIdx.x;
    int n = blockIdx.x;
    if (n == 0) { for (int i = tid; i < 1056; i += 256) bar[i] = 0u; }
    else if (n == 1) { pad0[tid] = 0u; }
    else if (n == 2) { pad1[tid] = 0u; }
    if (tid == 0) cnt = 0;
    __syncthreads();
    const float4* row = (const float4*)(C + (size_t)n * N_);
    for (int j4 = tid; j4 < N_ / 4; j4 += 256) {
        float4 v = row[j4];
        int base = j4 * 4;
        #pragma unroll
        for (int q = 0; q < 4; ++q) {
            float f = (q == 0) ? v.x : (q == 1) ? v.y : (q == 2) ? v.z : v.w;
            if (f != 0.0f) {
                uint32_t p = atomicAdd(&cnt, 1u);
                uint32_t m = (uint32_t)(base + q);
                if (p < DEG_SLOTS) nbr[n * DEG_SLOTS + p] = m * (uint32_t)B_;
            }
        }
    }
    __syncthreads();
    uint32_t c = min(cnt, (uint32_t)DEG_SLOTS);
    if (tid == 0) deg[n] = c;
    if (tid < DEG_SLOTS && (uint32_t)tid >= c)
        nbr[n * DEG_SLOTS + tid] = PAD_E;
}

// Two-hop grid barrier (round-12/16 proven): relaxed L3-homed atomics for
// arrivals + flag; exactly ONE acquire load (buffer_inv) per block per phase.
__device__ __forceinline__ void gbar(uint32_t* bar, uint32_t phase) {
    __syncthreads();                         // all waves' spike stores acked
    int tid = threadIdx.x, bid = blockIdx.x;
    if (tid == 0)
        __hip_atomic_fetch_add(&bar[(bid & (NCTR - 1)) * 32], 1u,
                               __ATOMIC_RELAXED, __HIP_MEMORY_SCOPE_AGENT);
    if (bid == 0) {
        if (tid < NCTR) {
            uint32_t tgt = (NBLK / NCTR) * phase;
            while (__hip_atomic_load(&bar[tid * 32], __ATOMIC_RELAXED,
                                     __HIP_MEMORY_SCOPE_AGENT) < tgt)
                __builtin_amdgcn_s_sleep(2);
        }
        __syncthreads();
        if (tid == 0)
            __hip_atomic_store(&bar[FLAGI], phase,
                               __ATOMIC_RELAXED, __HIP_MEMORY_SCOPE_AGENT);
    }
    if (tid == 0) {
        while (__hip_atomic_load(&bar[FLAGI], __ATOMIC_RELAXED,
                                 __HIP_MEMORY_SCOPE_AGENT) < phase)
            __builtin_amdgcn_s_sleep(2);
        (void)__hip_atomic_load(&bar[FLAGI], __ATOMIC_ACQUIRE,  // one buffer_inv
                                __HIP_MEMORY_SCOPE_AGENT);
    }
    __syncthreads();
}

// Persistent kernel: block = 8 neurons x ALL 1024 batches (1024 threads, 16
// waves); grid 512 = 2 blocks/CU = 32 waves/CU (max TLP; only ~10 KB LDS and
// <=64 VGPR so cooperative co-residency is far inside limits). Each neuron is
// owned by a PAIR of waves (512 batches each); refractory "any over batch" =
// one 2-entry LDS OR across the pair per step. Thread = 1 neuron x 8 batches;
// v in 8 VGPRs all 10 steps. Spike bytes via relaxed agent-scope b64 atomic
// stores (L3 write-through); gathers PLAIN uint2 loads freshened by the
// barrier's single acquire-inv.
__global__ __launch_bounds__(1024, 8) void persist_k(const float* __restrict__ ext,
                                                     const float* __restrict__ memb,
                                                     const float* __restrict__ thr,
                                                     const float* __restrict__ refr_in,
                                                     const uint32_t* __restrict__ deg,
                                                     const uint32_t* __restrict__ nbr,
                                                     unsigned char* __restrict__ sExp,
                                                     float* __restrict__ out,
                                                     uint32_t* bar) {
    __shared__ uint32_t s_nbr[8 * DEG_SLOTS];
    __shared__ uint32_t s_any[16];
    __shared__ unsigned char bt[8][1040];    // output transpose tile (padded rows)

    int bid = blockIdx.x;
    int n0 = bid * 8;
    int tid = threadIdx.x;
    int wv = tid >> 6, lane = tid & 63;      // 16 waves; pair (2*nn, 2*nn+1) <-> neuron
    int nn = wv >> 1, half = wv & 1;
    int n = n0 + nn;
    int bb = half * 512 + lane * 8;          // this thread's 8 batches

    if (tid < 8 * DEG_SLOTS) s_nbr[tid] = nbr[(size_t)n0 * DEG_SLOTS + tid];
    __syncthreads();

    float tn = thr[n];                       // wave-uniform
    float r  = refr_in[n];                   // per-wave copy of neuron refr state
    uint32_t dg = __builtin_amdgcn_readfirstlane(deg[n]);
    const uint32_t* lst = &s_nbr[nn * DEG_SLOTS];

    float v[8];
    {
        float mb = memb[n];
        #pragma unroll
        for (int i = 0; i < 8; ++i)          // column loads; lines shared across waves
            v[i] = __fadd_rn(mb, ext[(size_t)(bb + i) * N_ + n]);
    }

    uint32_t spk[2];

    // ---- step 0: external input only ----
    {
        uint32_t nb = (r != 0.0f) ? 0u : 1u;
        #pragma unroll
        for (int dw = 0; dw < 2; ++dw) {
            int sp0 = (v[dw * 4 + 0] > tn) && nb;
            int sp1 = (v[dw * 4 + 1] > tn) && nb;
            int sp2 = (v[dw * 4 + 2] > tn) && nb;
            int sp3 = (v[dw * 4 + 3] > tn) && nb;
            spk[dw] = (uint32_t)sp0 | ((uint32_t)sp1 << 8) |
                      ((uint32_t)sp2 << 16) | ((uint32_t)sp3 << 24);
            v[dw * 4 + 0] = __fmul_rn(sp0 ? 0.0f : v[dw * 4 + 0], 0.95f);
            v[dw * 4 + 1] = __fmul_rn(sp1 ? 0.0f : v[dw * 4 + 1], 0.95f);
            v[dw * 4 + 2] = __fmul_rn(sp2 ? 0.0f : v[dw * 4 + 2], 0.95f);
            v[dw * 4 + 3] = __fmul_rn(sp3 ? 0.0f : v[dw * 4 + 3], 0.95f);
        }
        unsigned long long p0 = (unsigned long long)spk[0] | ((unsigned long long)spk[1] << 32);
        __hip_atomic_store((unsigned long long*)(sExp + (size_t)n * B_ + bb), p0,
                           __ATOMIC_RELAXED, __HIP_MEMORY_SCOPE_AGENT);
        unsigned long long m64 = __ballot((spk[0] | spk[1]) != 0);
        if (lane == 0) s_any[wv] = (m64 != 0ull) ? 1u : 0u;
    }
    gbar(bar, 1);
    {
        int any = (s_any[2 * nn] | s_any[2 * nn + 1]) != 0u;
        r = any ? 3.0f : r;
        r = fminf(fmaxf(__fadd_rn(r, -1.0f), 0.0f), 10.0f);
        __syncthreads();                     // reads done before next s_any writes
    }

    // ---- steps 1..9 ----
    unsigned char* sprev = sExp;
    unsigned char* snext = sExp + (size_t)SEXP_BUF;
    for (int s = 1; s < NSTEPS_; ++s) {
        uint32_t nb = (r != 0.0f) ? 0u : 1u;
        uint32_t a0 = 0, a1 = 0;
        #pragma unroll
        for (int j = 0; j < UNR; ++j) {
            uint32_t e = lst[j];             // wave-uniform LDS broadcast
            uint2 d2 = *(const uint2*)(sprev + e + bb);
            a0 += d2.x; a1 += d2.y;
        }
        if (dg > UNR) {                      // wave-uniform tail
            for (uint32_t j = UNR; j < dg; ++j) {
                uint32_t e = lst[j];
                uint2 d2 = *(const uint2*)(sprev + e + bb);
                a0 += d2.x; a1 += d2.y;
            }
        }
        uint32_t accs[2] = {a0, a1};
        #pragma unroll
        for (int dw = 0; dw < 2; ++dw) {
            uint32_t acc = accs[dw];
            float v0 = __fadd_rn(v[dw * 4 + 0], __fmul_rn(0.1f, (float)( acc        & 255u)));
            float v1 = __fadd_rn(v[dw * 4 + 1], __fmul_rn(0.1f, (float)((acc >>  8) & 255u)));
            float v2 = __fadd_rn(v[dw * 4 + 2], __fmul_rn(0.1f, (float)((acc >> 16) & 255u)));
            float v3 = __fadd_rn(v[dw * 4 + 3], __fmul_rn(0.1f, (float)( acc >> 24        )));
            int sp0 = (v0 > tn) && nb;
            int sp1 = (v1 > tn) && nb;
            int sp2 = (v2 > tn) && nb;
            int sp3 = (v3 > tn) && nb;
            spk[dw] = (uint32_t)sp0 | ((uint32_t)sp1 << 8) |
                      ((uint32_t)sp2 << 16) | ((uint32_t)sp3 << 24);
            if (s < NSTEPS_ - 1) {
                v[dw * 4 + 0] = __fmul_rn(sp0 ? 0.0f : v0, 0.95f);
                v[dw * 4 + 1] = __fmul_rn(sp1 ? 0.0f : v1, 0.95f);
                v[dw * 4 + 2] = __fmul_rn(sp2 ? 0.0f : v2, 0.95f);
                v[dw * 4 + 3] = __fmul_rn(sp3 ? 0.0f : v3, 0.95f);
            }
        }
        if (s < NSTEPS_ - 1) {
            unsigned long long p0 = (unsigned long long)spk[0] | ((unsigned long long)spk[1] << 32);
            __hip_atomic_store((unsigned long long*)(snext + (size_t)n * B_ + bb), p0,
                               __ATOMIC_RELAXED, __HIP_MEMORY_SCOPE_AGENT);
            unsigned long long m64 = __ballot((spk[0] | spk[1]) != 0);
            if (lane == 0) s_any[wv] = (m64 != 0ull) ? 1u : 0u;
            gbar(bar, (uint32_t)s + 1);
            int any = (s_any[2 * nn] | s_any[2 * nn + 1]) != 0u;
            r = any ? 3.0f : r;
            r = fminf(fmaxf(__fadd_rn(r, -1.0f), 0.0f), 10.0f);
            __syncthreads();                 // reads done before next s_any writes
        }
        unsigned char* t = sprev; sprev = snext; snext = t;
    }

    // ---- output: step-9 spikes (in regs) -> byte tile -> [b][n] float4 ----
    *(uint2*)&bt[nn][bb] = make_uint2(spk[0], spk[1]);
    __syncthreads();
    #pragma unroll
    for (int p = 0; p < 2; ++p) {
        int i = tid + p * 1024;              // 2048 float4s: 1024 rows x 2 cols
        int rrow = i >> 1, c4 = (i & 1) * 4;
        float4 o;
        o.x = (float)bt[c4 + 0][rrow];
        o.y = (float)bt[c4 + 1][rrow];
        o.z = (float)bt[c4 + 2][rrow];
        o.w = (float)bt[c4 + 3][rrow];
        *(float4*)&out[(size_t)rrow * N_ + n0 + c4] = o;
    }
}

extern "C" void kernel_launch(void* const* d_in, const int* in_sizes, int n_in,
                              void* d_out, int out_size, void* d_ws, size_t ws_size,
                              hipStream_t stream) {
    const float* ext     = (const float*)d_in[0];
    const float* C       = (const float*)d_in[1];
    const float* memb    = (const float*)d_in[2];
    const float* thr     = (const float*)d_in[3];
    const float* refr_in = (const float*)d_in[4];

    char* ws = (char*)d_ws;
    uint32_t* bar    = (uint32_t*)(ws + OFF_BAR);
    uint32_t* deg    = (uint32_t*)(ws + OFF_DEG);
    uint32_t* nbr    = (uint32_t*)(ws + OFF_NBR);
    unsigned char* sExp = (unsigned char*)(ws + OFF_SEXP);
    float*    out    = (float*)d_out;

    build_k<<<dim3(N_), dim3(256), 0, stream>>>(
        C, deg, nbr, bar,
        (uint32_t*)(sExp + (size_t)N_ * B_),
        (uint32_t*)(sExp + (size_t)SEXP_BUF + (size_t)N_ * B_));

    void* args[] = {(void*)&ext, (void*)&memb, (void*)&thr, (void*)&refr_in,
                    (void*)&deg, (void*)&nbr, (void*)&sExp, (void*)&out,
                    (void*)&bar};
    hipLaunchCooperativeKernel((const void*)persist_k, dim3(NBLK), dim3(1024),
                               args, 0, stream);
}